// Round 4
// baseline (2275.140 us; speedup 1.0000x reference)
//
#include <hip/hip_runtime.h>

// Decoder_21208548508049: fused LIF-SNN decoder — round 4 (bisect + occupancy).
// ALL-f32. GEMM1 chain op-identical to round-1 PASS. GEMM2 reverted to the same
// proven f32 VALU chain (bisecting out the bf16/MFMA path of rounds 2-3).
// Spikes cross threads as a 512x32 bitmask in LDS (2 KB); g = x*(1-sp) is
// reconstructed during GEMM2 staging (select == multiply bit-exactly here).
//
// T=32,B=8,N=256,D=512. Block = one (b,n) token, 256 threads.
// LDS 34816 B -> 4 blocks/CU (139 KB of 160 KB), VGPR capped 128.

#define TT 32
#define BB 8
#define NN 256
#define DD 512

__global__ __launch_bounds__(256, 4) void lif_decoder_v4(
    const float* __restrict__ x,      // [T,B,N,D]
    const float* __restrict__ tr_mx,  // [B,N,D]
    const float* __restrict__ Wl,     // [D,D]
    const float* __restrict__ bl,     // [D]
    const float* __restrict__ Wr,     // [D,D]
    const float* __restrict__ br,     // [D]
    float* __restrict__ out)          // [T,B,N,D]
{
    __shared__ __align__(16) float xs[TT * 256];   // 32 KB: x halves, then g halves
    __shared__ unsigned msk[DD];                   // spike bits: (msk[d]>>t)&1

    const int tid = threadIdx.x;          // 0..255
    const int tok = blockIdx.x;           // 0..2047 == b*N+n
    const int e0  = tid * 2;
    const size_t base = (size_t)tok * DD;
    const size_t st   = (size_t)BB * NN * DD;   // t-stride

    float acc0[TT], acc1[TT];

    // ==== GEMM1: acc[t] = bl + sum_d x[t][d]*Wl[d][e]  (exact f32 FMA chain) ====
    {
        const float bl0 = bl[e0], bl1 = bl[e0 + 1];
        #pragma unroll
        for (int t = 0; t < TT; ++t) { acc0[t] = bl0; acc1[t] = bl1; }
    }

    #pragma unroll
    for (int h = 0; h < 2; ++h) {
        // stage x[t][h*256 .. h*256+255] for all t (8 float4/thread, coalesced)
        #pragma unroll
        for (int r = 0; r < 8; ++r) {
            const int flat = r * 256 + tid;
            const int t  = flat >> 6;
            const int c4 = flat & 63;
            const float4 v = *reinterpret_cast<const float4*>(
                &x[t * st + base + h * 256 + c4 * 4]);
            *reinterpret_cast<float4*>(&xs[t * 256 + c4 * 4]) = v;
        }
        __syncthreads();

        #pragma unroll 2
        for (int dd_ = 0; dd_ < 256; dd_ += 4) {
            const int d = h * 256 + dd_;
            const float2 w0 = *reinterpret_cast<const float2*>(&Wl[(size_t)(d + 0) * DD + e0]);
            const float2 w1 = *reinterpret_cast<const float2*>(&Wl[(size_t)(d + 1) * DD + e0]);
            const float2 w2 = *reinterpret_cast<const float2*>(&Wl[(size_t)(d + 2) * DD + e0]);
            const float2 w3 = *reinterpret_cast<const float2*>(&Wl[(size_t)(d + 3) * DD + e0]);
            #pragma unroll
            for (int t = 0; t < TT; ++t) {
                const float4 xv = *reinterpret_cast<const float4*>(&xs[t * 256 + dd_]);
                acc0[t] = fmaf(xv.x, w0.x, acc0[t]);
                acc1[t] = fmaf(xv.x, w0.y, acc1[t]);
                acc0[t] = fmaf(xv.y, w1.x, acc0[t]);
                acc1[t] = fmaf(xv.y, w1.y, acc1[t]);
                acc0[t] = fmaf(xv.z, w2.x, acc0[t]);
                acc1[t] = fmaf(xv.z, w2.y, acc1[t]);
                acc0[t] = fmaf(xv.w, w3.x, acc0[t]);
                acc1[t] = fmaf(xv.w, w3.y, acc1[t]);
            }
        }
        __syncthreads();   // reads of this half done before next overwrite
    }

    // ==== LIF recurrence (identical arithmetic to round-1 pass) -> spike mask ====
    {
        float m0 = tr_mx[base + e0];
        float m1 = tr_mx[base + e0 + 1];
        unsigned mc0 = 0u, mc1 = 0u;
        #pragma unroll
        for (int t = 0; t < TT; ++t) {
            m0 = m0 + (acc0[t] - m0) * 0.5f;
            m1 = m1 + (acc1[t] - m1) * 0.5f;
            const float s0 = (m0 - 1.0f > 0.0f) ? 1.0f : 0.0f;
            const float s1 = (m1 - 1.0f > 0.0f) ? 1.0f : 0.0f;
            mc0 |= (s0 > 0.0f) ? (1u << t) : 0u;
            mc1 |= (s1 > 0.0f) ? (1u << t) : 0u;
            m0 *= (1.0f - s0);
            m1 *= (1.0f - s1);
        }
        msk[e0]     = mc0;
        msk[e0 + 1] = mc1;
    }
    __syncthreads();

    // ==== GEMM2: out[t][e] = br + sum_d g[t][d]*Wr[d][e], g = sp?0:x  (f32) ====
    {
        const float br0 = br[e0], br1 = br[e0 + 1];
        #pragma unroll
        for (int t = 0; t < TT; ++t) { acc0[t] = br0; acc1[t] = br1; }
    }

    #pragma unroll
    for (int h = 0; h < 2; ++h) {
        // stage g[t][h*256 .. +255]: re-read x, zero where spike bit set
        #pragma unroll
        for (int r = 0; r < 8; ++r) {
            const int flat = r * 256 + tid;
            const int t  = flat >> 6;
            const int c4 = flat & 63;
            const int d0 = h * 256 + c4 * 4;
            float4 v = *reinterpret_cast<const float4*>(&x[t * st + base + d0]);
            const unsigned tb = 1u << t;
            v.x = (msk[d0 + 0] & tb) ? 0.0f : v.x;
            v.y = (msk[d0 + 1] & tb) ? 0.0f : v.y;
            v.z = (msk[d0 + 2] & tb) ? 0.0f : v.z;
            v.w = (msk[d0 + 3] & tb) ? 0.0f : v.w;
            *reinterpret_cast<float4*>(&xs[t * 256 + c4 * 4]) = v;
        }
        __syncthreads();

        #pragma unroll 2
        for (int dd_ = 0; dd_ < 256; dd_ += 4) {
            const int d = h * 256 + dd_;
            const float2 w0 = *reinterpret_cast<const float2*>(&Wr[(size_t)(d + 0) * DD + e0]);
            const float2 w1 = *reinterpret_cast<const float2*>(&Wr[(size_t)(d + 1) * DD + e0]);
            const float2 w2 = *reinterpret_cast<const float2*>(&Wr[(size_t)(d + 2) * DD + e0]);
            const float2 w3 = *reinterpret_cast<const float2*>(&Wr[(size_t)(d + 3) * DD + e0]);
            #pragma unroll
            for (int t = 0; t < TT; ++t) {
                const float4 gv = *reinterpret_cast<const float4*>(&xs[t * 256 + dd_]);
                acc0[t] = fmaf(gv.x, w0.x, acc0[t]);
                acc1[t] = fmaf(gv.x, w0.y, acc1[t]);
                acc0[t] = fmaf(gv.y, w1.x, acc0[t]);
                acc1[t] = fmaf(gv.y, w1.y, acc1[t]);
                acc0[t] = fmaf(gv.z, w2.x, acc0[t]);
                acc1[t] = fmaf(gv.z, w2.y, acc1[t]);
                acc0[t] = fmaf(gv.w, w3.x, acc0[t]);
                acc1[t] = fmaf(gv.w, w3.y, acc1[t]);
            }
        }
        __syncthreads();
    }

    // ==== store (coalesced float2) ====
    #pragma unroll
    for (int t = 0; t < TT; ++t) {
        float2 v;
        v.x = acc0[t];
        v.y = acc1[t];
        *reinterpret_cast<float2*>(&out[t * st + base + e0]) = v;
    }
}

extern "C" void kernel_launch(void* const* d_in, const int* in_sizes, int n_in,
                              void* d_out, int out_size, void* d_ws, size_t ws_size,
                              hipStream_t stream) {
    const float* x     = (const float*)d_in[0];
    const float* tr_mx = (const float*)d_in[1];
    const float* Wl    = (const float*)d_in[2];
    const float* bl    = (const float*)d_in[3];
    const float* Wr    = (const float*)d_in[4];
    const float* br    = (const float*)d_in[5];
    float* out = (float*)d_out;

    dim3 grid(BB * NN);
    dim3 block(256);
    lif_decoder_v4<<<grid, block, 0, stream>>>(x, tr_mx, Wl, bl, Wr, br, out);
}

// Round 5
// 1287.496 us; speedup vs baseline: 1.7671x; 1.7671x over previous
//
#include <hip/hip_runtime.h>

// Decoder_21208548508049 — round 5: all-f32, spill-proof, full occupancy.
// Lesson from round 4: launch_bounds cap near the live-set size made the
// allocator round DOWN to 64 VGPRs and spill the 64-float accumulator
// (WRITE_SIZE 6.5 GB of scratch). Fix structurally: thread owns ONE e-column
// and t is processed in two halves of 16 -> acc[16], live set ~50 regs,
// fits the 64-VGPR occupancy step with slack. 512-thread blocks.
//
// GEMM1 chain + LIF arithmetic op-identical to the round-1/round-4 PASS
// (bias init, d-ascending fmaf order) -> spike pattern bit-identical.
//
// T=32,B=8,N=256,D=512. Block = one (b,n) token, 512 threads (e = tid).
// LDS 18432 B; 4 blocks/CU x 8 waves = 32 waves/CU (100% occupancy).

#define TT 32
#define TH 16
#define BB 8
#define NN 256
#define DD 512

__global__ __launch_bounds__(512, 8) void lif_decoder_v5(
    const float* __restrict__ x,      // [T,B,N,D]
    const float* __restrict__ tr_mx,  // [B,N,D]
    const float* __restrict__ Wl,     // [D,D]
    const float* __restrict__ bl,     // [D]
    const float* __restrict__ Wr,     // [D,D]
    const float* __restrict__ br,     // [D]
    float* __restrict__ out)          // [T,B,N,D]
{
    __shared__ __align__(16) float xs[TH * 256];   // 16 KB: one (t-half, d-half) tile
    __shared__ unsigned msk[DD];                   // 2 KB: spike bits, (msk[e]>>t)&1

    const int tid = threadIdx.x;          // 0..511 == owned e column
    const int tok = blockIdx.x;           // 0..2047 == b*N+n
    const size_t base = (size_t)tok * DD;
    const size_t st   = (size_t)BB * NN * DD;   // t-stride

    float acc[TH];
    const float blv = bl[tid];
    float m = tr_mx[base + tid];
    unsigned mc = 0u;

    // ==== GEMM1 + LIF, t in two halves (recurrence state m carried) ====
    #pragma unroll 1
    for (int th = 0; th < 2; ++th) {
        #pragma unroll
        for (int i = 0; i < TH; ++i) acc[i] = blv;

        #pragma unroll 1
        for (int h = 0; h < 2; ++h) {
            // stage x[th*16 .. +15][h*256 .. +255]  (2 float4/thread, coalesced)
            #pragma unroll
            for (int r = 0; r < 2; ++r) {
                const int flat = r * 512 + tid;        // 0..1023
                const int tl = flat >> 6;              // 0..15
                const int c4 = flat & 63;
                const float4 v = *reinterpret_cast<const float4*>(
                    &x[(size_t)(th * TH + tl) * st + base + h * 256 + c4 * 4]);
                *reinterpret_cast<float4*>(&xs[tl * 256 + c4 * 4]) = v;
            }
            __syncthreads();

            #pragma unroll 2
            for (int dd_ = 0; dd_ < 256; dd_ += 4) {
                const int d = h * 256 + dd_;
                const float w0 = Wl[(size_t)(d + 0) * DD + tid];
                const float w1 = Wl[(size_t)(d + 1) * DD + tid];
                const float w2 = Wl[(size_t)(d + 2) * DD + tid];
                const float w3 = Wl[(size_t)(d + 3) * DD + tid];
                #pragma unroll
                for (int i = 0; i < TH; ++i) {
                    const float4 xv = *reinterpret_cast<const float4*>(&xs[i * 256 + dd_]);
                    acc[i] = fmaf(xv.x, w0, acc[i]);
                    acc[i] = fmaf(xv.y, w1, acc[i]);
                    acc[i] = fmaf(xv.z, w2, acc[i]);
                    acc[i] = fmaf(xv.w, w3, acc[i]);
                }
            }
            __syncthreads();   // xs reads done before next stage overwrites
        }

        // LIF for this t-half (identical arithmetic to round-1/4 pass)
        #pragma unroll
        for (int i = 0; i < TH; ++i) {
            m = m + (acc[i] - m) * 0.5f;
            const float s = (m - 1.0f > 0.0f) ? 1.0f : 0.0f;
            mc |= (s > 0.0f) ? (1u << (th * TH + i)) : 0u;
            m *= (1.0f - s);
        }
    }
    msk[tid] = mc;
    __syncthreads();

    // ==== GEMM2: out[t][e] = br + sum_d g[t][d]*Wr[d][e], g = sp?0:x ====
    const float brv = br[tid];
    #pragma unroll 1
    for (int th = 0; th < 2; ++th) {
        #pragma unroll
        for (int i = 0; i < TH; ++i) acc[i] = brv;

        #pragma unroll 1
        for (int h = 0; h < 2; ++h) {
            // stage g tile: re-read x, zero where spike bit set
            #pragma unroll
            for (int r = 0; r < 2; ++r) {
                const int flat = r * 512 + tid;
                const int tl = flat >> 6;
                const int c4 = flat & 63;
                const int d0 = h * 256 + c4 * 4;
                float4 v = *reinterpret_cast<const float4*>(
                    &x[(size_t)(th * TH + tl) * st + base + d0]);
                const unsigned tb = 1u << (th * TH + tl);
                const uint4 mv = *reinterpret_cast<const uint4*>(&msk[d0]);
                v.x = (mv.x & tb) ? 0.0f : v.x;
                v.y = (mv.y & tb) ? 0.0f : v.y;
                v.z = (mv.z & tb) ? 0.0f : v.z;
                v.w = (mv.w & tb) ? 0.0f : v.w;
                *reinterpret_cast<float4*>(&xs[tl * 256 + c4 * 4]) = v;
            }
            __syncthreads();

            #pragma unroll 2
            for (int dd_ = 0; dd_ < 256; dd_ += 4) {
                const int d = h * 256 + dd_;
                const float w0 = Wr[(size_t)(d + 0) * DD + tid];
                const float w1 = Wr[(size_t)(d + 1) * DD + tid];
                const float w2 = Wr[(size_t)(d + 2) * DD + tid];
                const float w3 = Wr[(size_t)(d + 3) * DD + tid];
                #pragma unroll
                for (int i = 0; i < TH; ++i) {
                    const float4 gv = *reinterpret_cast<const float4*>(&xs[i * 256 + dd_]);
                    acc[i] = fmaf(gv.x, w0, acc[i]);
                    acc[i] = fmaf(gv.y, w1, acc[i]);
                    acc[i] = fmaf(gv.z, w2, acc[i]);
                    acc[i] = fmaf(gv.w, w3, acc[i]);
                }
            }
            __syncthreads();
        }

        // store this t-half (lanes -> consecutive e, coalesced)
        #pragma unroll
        for (int i = 0; i < TH; ++i)
            out[(size_t)(th * TH + i) * st + base + tid] = acc[i];
    }
}

extern "C" void kernel_launch(void* const* d_in, const int* in_sizes, int n_in,
                              void* d_out, int out_size, void* d_ws, size_t ws_size,
                              hipStream_t stream) {
    const float* x     = (const float*)d_in[0];
    const float* tr_mx = (const float*)d_in[1];
    const float* Wl    = (const float*)d_in[2];
    const float* bl    = (const float*)d_in[3];
    const float* Wr    = (const float*)d_in[4];
    const float* br    = (const float*)d_in[5];
    float* out = (float*)d_out;

    dim3 grid(BB * NN);
    dim3 block(512);
    lif_decoder_v5<<<grid, block, 0, stream>>>(x, tr_mx, Wl, bl, Wr, br, out);
}

// Round 6
// 937.953 us; speedup vs baseline: 2.4256x; 1.3727x over previous
//
#include <hip/hip_runtime.h>

// Decoder_21208548508049 — round 6: all-f32, register-tiled 4e x 8t.
// Round-4 lesson: acc[64] @ 64-VGPR cap -> scratch spills (WRITE 6.5GB).
// Round-5 lesson: acc[16] @ VGPR=32 -> allocator emitted ~2.3 extra VALU/FMA
//   (addr remat + mov) and serialized 1 ds_read per 4 FMA; 97% VALUBusy at
//   29% of f32 peak. Fix: 16 FMA per ds_read_b128, live set ~80 regs,
//   cap 128 VGPR (16 waves/CU).
//
// Thread owns e in [4*tid, 4*tid+4) and loops t in 4 chunks of 8 (LIF state
// m[4] carried in-thread -> per-(t,e) fmaf chain order identical to the
// round-1/4/5 PASSES -> spike pattern bit-identical -> absmax 0.0).
//
// T=32,B=8,N=256,D=512. Block = one (b,n) token, 128 threads.
// LDS: xs[8][512] f32 (16KB) + msk[512] (2KB). 8 blocks/CU.

#define TT 32
#define CH 8     // t-chunk
#define BB 8
#define NN 256
#define DD 512

__global__ __launch_bounds__(128, 4) void lif_decoder_v6(
    const float* __restrict__ x,      // [T,B,N,D]
    const float* __restrict__ tr_mx,  // [B,N,D]
    const float* __restrict__ Wl,     // [D,D]
    const float* __restrict__ bl,     // [D]
    const float* __restrict__ Wr,     // [D,D]
    const float* __restrict__ br,     // [D]
    float* __restrict__ out)          // [T,B,N,D]
{
    __shared__ __align__(16) float xs[CH * DD];    // 16 KB: one t-chunk, full d
    __shared__ __align__(16) unsigned msk[DD];     // 2 KB: (msk[d]>>t)&1

    const int tid = threadIdx.x;          // 0..127
    const int tok = blockIdx.x;           // 0..2047 == b*N+n
    const int e0  = tid * 4;              // owned e-columns e0..e0+3
    const size_t base = (size_t)tok * DD;
    const size_t st   = (size_t)BB * NN * DD;   // t-stride

    float acc[CH][4];

    // ---- LIF state ----
    float4 m4 = *reinterpret_cast<const float4*>(&tr_mx[base + e0]);
    float m[4] = {m4.x, m4.y, m4.z, m4.w};
    unsigned mc[4] = {0u, 0u, 0u, 0u};

    const float4 blv = *reinterpret_cast<const float4*>(&bl[e0]);
    const float blr[4] = {blv.x, blv.y, blv.z, blv.w};

    // ==== GEMM1 + LIF over 4 t-chunks ====
    #pragma unroll 1
    for (int tg = 0; tg < 4; ++tg) {
        // stage x[tg*8 .. +7][0..511]  (8 float4/thread, coalesced)
        #pragma unroll
        for (int r = 0; r < 8; ++r) {
            const int flat = r * 128 + tid;        // 0..1023
            const int tl = flat >> 7;              // 0..7
            const int c4 = flat & 127;
            const float4 v = *reinterpret_cast<const float4*>(
                &x[(size_t)(tg * CH + tl) * st + base + c4 * 4]);
            *reinterpret_cast<float4*>(&xs[tl * DD + c4 * 4]) = v;
        }
        __syncthreads();

        #pragma unroll
        for (int i = 0; i < CH; ++i)
            #pragma unroll
            for (int e = 0; e < 4; ++e) acc[i][e] = blr[e];

        #pragma unroll 2
        for (int d = 0; d < DD; d += 4) {
            const float4 w0 = *reinterpret_cast<const float4*>(&Wl[(size_t)(d + 0) * DD + e0]);
            const float4 w1 = *reinterpret_cast<const float4*>(&Wl[(size_t)(d + 1) * DD + e0]);
            const float4 w2 = *reinterpret_cast<const float4*>(&Wl[(size_t)(d + 2) * DD + e0]);
            const float4 w3 = *reinterpret_cast<const float4*>(&Wl[(size_t)(d + 3) * DD + e0]);
            #pragma unroll
            for (int i = 0; i < CH; ++i) {
                const float4 xv = *reinterpret_cast<const float4*>(&xs[i * DD + d]);
                // d-ascending fmaf chain per (t,e): identical to prior passes
                acc[i][0] = fmaf(xv.x, w0.x, acc[i][0]);
                acc[i][1] = fmaf(xv.x, w0.y, acc[i][1]);
                acc[i][2] = fmaf(xv.x, w0.z, acc[i][2]);
                acc[i][3] = fmaf(xv.x, w0.w, acc[i][3]);
                acc[i][0] = fmaf(xv.y, w1.x, acc[i][0]);
                acc[i][1] = fmaf(xv.y, w1.y, acc[i][1]);
                acc[i][2] = fmaf(xv.y, w1.z, acc[i][2]);
                acc[i][3] = fmaf(xv.y, w1.w, acc[i][3]);
                acc[i][0] = fmaf(xv.z, w2.x, acc[i][0]);
                acc[i][1] = fmaf(xv.z, w2.y, acc[i][1]);
                acc[i][2] = fmaf(xv.z, w2.z, acc[i][2]);
                acc[i][3] = fmaf(xv.z, w2.w, acc[i][3]);
                acc[i][0] = fmaf(xv.w, w3.x, acc[i][0]);
                acc[i][1] = fmaf(xv.w, w3.y, acc[i][1]);
                acc[i][2] = fmaf(xv.w, w3.z, acc[i][2]);
                acc[i][3] = fmaf(xv.w, w3.w, acc[i][3]);
            }
        }
        __syncthreads();   // xs reads done before next chunk overwrites

        // LIF for this chunk (arithmetic identical to prior passes)
        #pragma unroll
        for (int i = 0; i < CH; ++i) {
            const int t = tg * CH + i;
            #pragma unroll
            for (int e = 0; e < 4; ++e) {
                m[e] = m[e] + (acc[i][e] - m[e]) * 0.5f;
                const float s = (m[e] - 1.0f > 0.0f) ? 1.0f : 0.0f;
                mc[e] |= (s > 0.0f) ? (1u << t) : 0u;
                m[e] *= (1.0f - s);
            }
        }
    }

    #pragma unroll
    for (int e = 0; e < 4; ++e) msk[e0 + e] = mc[e];
    __syncthreads();

    // ==== GEMM2 over 4 t-chunks: g = sp?0:x ====
    const float4 brv = *reinterpret_cast<const float4*>(&br[e0]);
    const float brr[4] = {brv.x, brv.y, brv.z, brv.w};

    #pragma unroll 1
    for (int tg = 0; tg < 4; ++tg) {
        // stage g[tg*8 .. +7][0..511]: re-read x, zero where spike bit set
        #pragma unroll
        for (int r = 0; r < 8; ++r) {
            const int flat = r * 128 + tid;
            const int tl = flat >> 7;
            const int c4 = flat & 127;
            const int d0 = c4 * 4;
            float4 v = *reinterpret_cast<const float4*>(
                &x[(size_t)(tg * CH + tl) * st + base + d0]);
            const unsigned tb = 1u << (tg * CH + tl);
            const uint4 mv = *reinterpret_cast<const uint4*>(&msk[d0]);
            v.x = (mv.x & tb) ? 0.0f : v.x;
            v.y = (mv.y & tb) ? 0.0f : v.y;
            v.z = (mv.z & tb) ? 0.0f : v.z;
            v.w = (mv.w & tb) ? 0.0f : v.w;
            *reinterpret_cast<float4*>(&xs[tl * DD + d0]) = v;
        }
        __syncthreads();

        #pragma unroll
        for (int i = 0; i < CH; ++i)
            #pragma unroll
            for (int e = 0; e < 4; ++e) acc[i][e] = brr[e];

        #pragma unroll 2
        for (int d = 0; d < DD; d += 4) {
            const float4 w0 = *reinterpret_cast<const float4*>(&Wr[(size_t)(d + 0) * DD + e0]);
            const float4 w1 = *reinterpret_cast<const float4*>(&Wr[(size_t)(d + 1) * DD + e0]);
            const float4 w2 = *reinterpret_cast<const float4*>(&Wr[(size_t)(d + 2) * DD + e0]);
            const float4 w3 = *reinterpret_cast<const float4*>(&Wr[(size_t)(d + 3) * DD + e0]);
            #pragma unroll
            for (int i = 0; i < CH; ++i) {
                const float4 gv = *reinterpret_cast<const float4*>(&xs[i * DD + d]);
                acc[i][0] = fmaf(gv.x, w0.x, acc[i][0]);
                acc[i][1] = fmaf(gv.x, w0.y, acc[i][1]);
                acc[i][2] = fmaf(gv.x, w0.z, acc[i][2]);
                acc[i][3] = fmaf(gv.x, w0.w, acc[i][3]);
                acc[i][0] = fmaf(gv.y, w1.x, acc[i][0]);
                acc[i][1] = fmaf(gv.y, w1.y, acc[i][1]);
                acc[i][2] = fmaf(gv.y, w1.z, acc[i][2]);
                acc[i][3] = fmaf(gv.y, w1.w, acc[i][3]);
                acc[i][0] = fmaf(gv.z, w2.x, acc[i][0]);
                acc[i][1] = fmaf(gv.z, w2.y, acc[i][1]);
                acc[i][2] = fmaf(gv.z, w2.z, acc[i][2]);
                acc[i][3] = fmaf(gv.z, w2.w, acc[i][3]);
                acc[i][0] = fmaf(gv.w, w3.x, acc[i][0]);
                acc[i][1] = fmaf(gv.w, w3.y, acc[i][1]);
                acc[i][2] = fmaf(gv.w, w3.z, acc[i][2]);
                acc[i][3] = fmaf(gv.w, w3.w, acc[i][3]);
            }
        }
        __syncthreads();

        // store chunk (float4 per t, coalesced 2KB/row across 128 threads)
        #pragma unroll
        for (int i = 0; i < CH; ++i) {
            float4 v;
            v.x = acc[i][0]; v.y = acc[i][1]; v.z = acc[i][2]; v.w = acc[i][3];
            *reinterpret_cast<float4*>(
                &out[(size_t)(tg * CH + i) * st + base + e0]) = v;
        }
    }
}

extern "C" void kernel_launch(void* const* d_in, const int* in_sizes, int n_in,
                              void* d_out, int out_size, void* d_ws, size_t ws_size,
                              hipStream_t stream) {
    const float* x     = (const float*)d_in[0];
    const float* tr_mx = (const float*)d_in[1];
    const float* Wl    = (const float*)d_in[2];
    const float* bl    = (const float*)d_in[3];
    const float* Wr    = (const float*)d_in[4];
    const float* br    = (const float*)d_in[5];
    float* out = (float*)d_out;

    dim3 grid(BB * NN);
    dim3 block(128);
    lif_decoder_v6<<<grid, block, 0, stream>>>(x, tr_mx, Wl, bl, Wr, br, out);
}

// Round 7
// 768.356 us; speedup vs baseline: 2.9611x; 1.2207x over previous
//
#include <hip/hip_runtime.h>
#include <hip/hip_bf16.h>

// Decoder_21208548508049 — round 7.
// Phase A: round-6 GEMM1 (exact f32 FMA chain) + LIF -> spike bitmask. VERBATIM.
// Phase B: GEMM2 via bf16 MFMA, A-frags built IN-REGISTER from global x +
//   LDS bitmask (no LDS-staged-g fragment machinery — the rounds-2/3 suspect).
//   B-frags from bf16-transposed Wt (d_ws) or direct f32 Wr fallback.
// GEMM2 is threshold-free: bf16 quantization error ~0.014 << 0.111 threshold.
//
// T=32,B=8,N=256,D=512. Block = one (b,n) token, 128 threads (2 waves).

#define TT 32
#define CH 8     // t-chunk for phase A
#define BB 8
#define NN 256
#define DD 512

typedef __attribute__((ext_vector_type(8))) short short8;
typedef __attribute__((ext_vector_type(4))) float f32x4;

__device__ __forceinline__ unsigned short f2bf(float f) {
    __hip_bfloat16 h = __float2bfloat16(f);
    return *reinterpret_cast<unsigned short*>(&h);
}

// ---- pre-kernel: Wt[p][d] = bf16(Wr[d][p]) ----
__global__ void cast_transpose_wr(const float* __restrict__ Wr,
                                  unsigned short* __restrict__ Wt) {
    int idx = blockIdx.x * 256 + threadIdx.x;      // 0..262143
    int d = idx >> 9;
    int p = idx & 511;
    Wt[p * DD + d] = f2bf(Wr[idx]);
}

template<bool UW>
__global__ __launch_bounds__(128, 2) void lif_decoder_v7(
    const float* __restrict__ x,      // [T,B,N,D]
    const float* __restrict__ tr_mx,  // [B,N,D]
    const float* __restrict__ Wl,     // [D,D]
    const float* __restrict__ bl,     // [D]
    const float* __restrict__ Wr,     // [D,D]
    const float* __restrict__ br,     // [D]
    const unsigned short* __restrict__ Wt,  // [D,D] bf16 transposed (if UW)
    float* __restrict__ out)          // [T,B,N,D]
{
    __shared__ __align__(16) float xs[CH * DD];    // 16 KB
    __shared__ __align__(16) unsigned msk[DD];     // 2 KB: (msk[d]>>t)&1

    const int tid = threadIdx.x;          // 0..127
    const int tok = blockIdx.x;           // 0..2047 == b*N+n
    const int e0  = tid * 4;
    const size_t base = (size_t)tok * DD;
    const size_t st   = (size_t)BB * NN * DD;

    // ================= Phase A: GEMM1 + LIF (round-6 verbatim) =================
    {
        float acc[CH][4];
        float4 m4 = *reinterpret_cast<const float4*>(&tr_mx[base + e0]);
        float m[4] = {m4.x, m4.y, m4.z, m4.w};
        unsigned mc[4] = {0u, 0u, 0u, 0u};

        const float4 blv = *reinterpret_cast<const float4*>(&bl[e0]);
        const float blr[4] = {blv.x, blv.y, blv.z, blv.w};

        #pragma unroll 1
        for (int tg = 0; tg < 4; ++tg) {
            #pragma unroll
            for (int r = 0; r < 8; ++r) {
                const int flat = r * 128 + tid;
                const int tl = flat >> 7;
                const int c4 = flat & 127;
                const float4 v = *reinterpret_cast<const float4*>(
                    &x[(size_t)(tg * CH + tl) * st + base + c4 * 4]);
                *reinterpret_cast<float4*>(&xs[tl * DD + c4 * 4]) = v;
            }
            __syncthreads();

            #pragma unroll
            for (int i = 0; i < CH; ++i)
                #pragma unroll
                for (int e = 0; e < 4; ++e) acc[i][e] = blr[e];

            #pragma unroll 2
            for (int d = 0; d < DD; d += 4) {
                const float4 w0 = *reinterpret_cast<const float4*>(&Wl[(size_t)(d + 0) * DD + e0]);
                const float4 w1 = *reinterpret_cast<const float4*>(&Wl[(size_t)(d + 1) * DD + e0]);
                const float4 w2 = *reinterpret_cast<const float4*>(&Wl[(size_t)(d + 2) * DD + e0]);
                const float4 w3 = *reinterpret_cast<const float4*>(&Wl[(size_t)(d + 3) * DD + e0]);
                #pragma unroll
                for (int i = 0; i < CH; ++i) {
                    const float4 xv = *reinterpret_cast<const float4*>(&xs[i * DD + d]);
                    acc[i][0] = fmaf(xv.x, w0.x, acc[i][0]);
                    acc[i][1] = fmaf(xv.x, w0.y, acc[i][1]);
                    acc[i][2] = fmaf(xv.x, w0.z, acc[i][2]);
                    acc[i][3] = fmaf(xv.x, w0.w, acc[i][3]);
                    acc[i][0] = fmaf(xv.y, w1.x, acc[i][0]);
                    acc[i][1] = fmaf(xv.y, w1.y, acc[i][1]);
                    acc[i][2] = fmaf(xv.y, w1.z, acc[i][2]);
                    acc[i][3] = fmaf(xv.y, w1.w, acc[i][3]);
                    acc[i][0] = fmaf(xv.z, w2.x, acc[i][0]);
                    acc[i][1] = fmaf(xv.z, w2.y, acc[i][1]);
                    acc[i][2] = fmaf(xv.z, w2.z, acc[i][2]);
                    acc[i][3] = fmaf(xv.z, w2.w, acc[i][3]);
                    acc[i][0] = fmaf(xv.w, w3.x, acc[i][0]);
                    acc[i][1] = fmaf(xv.w, w3.y, acc[i][1]);
                    acc[i][2] = fmaf(xv.w, w3.z, acc[i][2]);
                    acc[i][3] = fmaf(xv.w, w3.w, acc[i][3]);
                }
            }
            __syncthreads();

            #pragma unroll
            for (int i = 0; i < CH; ++i) {
                const int t = tg * CH + i;
                #pragma unroll
                for (int e = 0; e < 4; ++e) {
                    m[e] = m[e] + (acc[i][e] - m[e]) * 0.5f;
                    const float s = (m[e] - 1.0f > 0.0f) ? 1.0f : 0.0f;
                    mc[e] |= (s > 0.0f) ? (1u << t) : 0u;
                    m[e] *= (1.0f - s);
                }
            }
        }

        #pragma unroll
        for (int e = 0; e < 4; ++e) msk[e0 + e] = mc[e];
    }
    __syncthreads();

    // ================= Phase B: GEMM2 via bf16 MFMA =================
    // out[t][p] = br[p] + sum_d g[t][d]*Wr[d][p],  g = sp ? 0 : x  (bf16 A/B)
    {
        const int lane = tid & 63;
        const int wv   = tid >> 6;            // wave 0: t 0..15, wave 1: t 16..31
        const int lcol = lane & 15;
        const int lkg  = lane >> 4;           // 0..3
        const int tA   = wv * 16 + lcol;      // A-frag row (t) this lane supplies

        // --- build all 16 A-frags in-register from global x + LDS mask bits ---
        short8 af[16];                        // 64 VGPR; statically indexed
        #pragma unroll
        for (int ks = 0; ks < 16; ++ks) {
            const int kb = ks * 32 + lkg * 8;
            const float4 x0 = *reinterpret_cast<const float4*>(&x[(size_t)tA * st + base + kb]);
            const float4 x1 = *reinterpret_cast<const float4*>(&x[(size_t)tA * st + base + kb + 4]);
            const uint4 m0 = *reinterpret_cast<const uint4*>(&msk[kb]);
            const uint4 m1 = *reinterpret_cast<const uint4*>(&msk[kb + 4]);
            short8 a;
            a[0] = (short)f2bf(((m0.x >> tA) & 1u) ? 0.0f : x0.x);
            a[1] = (short)f2bf(((m0.y >> tA) & 1u) ? 0.0f : x0.y);
            a[2] = (short)f2bf(((m0.z >> tA) & 1u) ? 0.0f : x0.z);
            a[3] = (short)f2bf(((m0.w >> tA) & 1u) ? 0.0f : x0.w);
            a[4] = (short)f2bf(((m1.x >> tA) & 1u) ? 0.0f : x1.x);
            a[5] = (short)f2bf(((m1.y >> tA) & 1u) ? 0.0f : x1.y);
            a[6] = (short)f2bf(((m1.z >> tA) & 1u) ? 0.0f : x1.z);
            a[7] = (short)f2bf(((m1.w >> tA) & 1u) ? 0.0f : x1.w);
            af[ks] = a;
        }

        // --- 4 passes of 128 output cols; acc[8] tiles of 16 cols each ---
        #pragma unroll 1
        for (int pass = 0; pass < 4; ++pass) {
            const int colb = pass * 128;
            f32x4 acc[8];
            #pragma unroll
            for (int nt = 0; nt < 8; ++nt) {
                const float b = br[colb + nt * 16 + lcol];
                acc[nt] = (f32x4){b, b, b, b};
            }

            #pragma unroll
            for (int ks = 0; ks < 16; ++ks) {
                const int kb = ks * 32 + lkg * 8;
                #pragma unroll
                for (int nt = 0; nt < 8; ++nt) {
                    const int col = colb + nt * 16 + lcol;
                    short8 bf;
                    if (UW) {
                        bf = *reinterpret_cast<const short8*>(&Wt[(size_t)col * DD + kb]);
                    } else {
                        #pragma unroll
                        for (int j = 0; j < 8; ++j)
                            bf[j] = (short)f2bf(Wr[(size_t)(kb + j) * DD + col]);
                    }
                    acc[nt] = __builtin_amdgcn_mfma_f32_16x16x32_bf16(af[ks], bf, acc[nt], 0, 0, 0);
                }
            }

            // epilogue: C/D layout col=lane&15, row=(lane>>4)*4+r (m89-verified)
            #pragma unroll
            for (int nt = 0; nt < 8; ++nt) {
                const int col = colb + nt * 16 + lcol;
                #pragma unroll
                for (int r = 0; r < 4; ++r) {
                    const int t = wv * 16 + lkg * 4 + r;
                    out[(size_t)t * st + base + col] = acc[nt][r];
                }
            }
        }
    }
}

extern "C" void kernel_launch(void* const* d_in, const int* in_sizes, int n_in,
                              void* d_out, int out_size, void* d_ws, size_t ws_size,
                              hipStream_t stream) {
    const float* x     = (const float*)d_in[0];
    const float* tr_mx = (const float*)d_in[1];
    const float* Wl    = (const float*)d_in[2];
    const float* bl    = (const float*)d_in[3];
    const float* Wr    = (const float*)d_in[4];
    const float* br    = (const float*)d_in[5];
    float* out = (float*)d_out;

    const size_t wt_bytes = (size_t)DD * DD * 2;
    dim3 grid(BB * NN);
    dim3 block(128);

    if (ws_size >= wt_bytes) {
        unsigned short* Wt = (unsigned short*)d_ws;
        cast_transpose_wr<<<dim3(1024), dim3(256), 0, stream>>>(Wr, Wt);
        lif_decoder_v7<true><<<grid, block, 0, stream>>>(x, tr_mx, Wl, bl, Wr, br, Wt, out);
    } else {
        lif_decoder_v7<false><<<grid, block, 0, stream>>>(x, tr_mx, Wl, bl, Wr, br, nullptr, out);
    }
}